// Round 2
// baseline (1250.278 us; speedup 1.0000x reference)
//
#include <hip/hip_runtime.h>
#include <stdint.h>

#define F_FRAMES 1296
#define JC 24
#define CH 256
#define NH 8
#define EMAX 120
#define M1 31104
#define N1 1536
#define K1 256
#define M2 22144
#define MREAL 22032
#define K2 1280
#define N2 256

typedef __attribute__((ext_vector_type(8))) short s8v;
typedef __attribute__((ext_vector_type(4))) short s4v;
typedef __attribute__((ext_vector_type(4))) float f4v;

#define GLOBAL_AS __attribute__((address_space(1)))
#define LDS_AS __attribute__((address_space(3)))

__device__ __forceinline__ float b2f(uint16_t u){
  union { float f; uint32_t u; } v; v.u = ((uint32_t)u) << 16; return v.f;
}
__device__ __forceinline__ uint16_t f2b(float f){
  union { float f; uint32_t u; } v; v.f = f;
  uint32_t u = v.u;
  uint32_t r = (u + 0x7fffu + ((u >> 16) & 1u)) >> 16;
  return (uint16_t)r;
}

// ---------------- dtype detection -------------------------------------------
// bf16 stream: ~100% of words have exponent field in [115,131] (N(0,1) data).
// f32 stream: high halves pass (~100%), low mantissa halves ~7% -> ~53% total.
__global__ __launch_bounds__(256) void detect_kernel(const uint16_t* __restrict__ x,
                                                     int* __restrict__ flag){
  __shared__ int cnt;
  if (threadIdx.x == 0) cnt = 0;
  __syncthreads();
  int good = 0;
  for (int i = threadIdx.x; i < 512; i += 256){
    uint16_t v = x[i];
    int e = (v >> 7) & 0xFF;
    good += (e >= 115 && e <= 131) ? 1 : 0;
  }
  atomicAdd(&cnt, good);
  __syncthreads();
  if (threadIdx.x == 0) *flag = (cnt >= 400) ? 1 : 0;
}

// ---------------- convert all float inputs into a bf16 arena ----------------
struct Ptrs { const void* p[21]; };

__constant__ int c_off[22] = {
  0, 5640192, 6033408, 6033472, 6033728, 6033984, 6427200, 6427264, 6427520,
  6427776, 6820992, 6821056, 6821312, 6821568, 7214784, 7214848, 7215104,
  7215360, 7543040, 7543296, 7543552, 7543808};

__global__ __launch_bounds__(256) void convert_kernel(Ptrs ptrs,
        const int* __restrict__ flag, uint16_t* __restrict__ arena){
  long base = ((long)blockIdx.x * 256 + threadIdx.x) * 8;
  if (base >= 7543808L) return;
  int seg = 0;
  while (c_off[seg + 1] <= base) seg++;
  long loc = base - c_off[seg];
  if (*flag){
    *(s8v*)(arena + base) = *(const s8v*)((const uint16_t*)ptrs.p[seg] + loc);
  } else {
    const float* s = (const float*)ptrs.p[seg] + loc;
    f4v a = *(const f4v*)s;
    f4v b = *(const f4v*)(s + 4);
    s8v o;
    #pragma unroll
    for (int u = 0; u < 4; u++){ o[u] = (short)f2b(a[u]); o[4+u] = (short)f2b(b[u]); }
    *(s8v*)(arena + base) = o;
  }
}

// ---------------- prep: build xc0 (padded x), y[:,0:256]=x, zero y pad rows ----
__global__ __launch_bounds__(256) void prep_kernel(const uint16_t* __restrict__ x,
                     uint16_t* __restrict__ xc0, uint16_t* __restrict__ y){
  long i = (long)blockIdx.x * 256 + threadIdx.x;
  const long n1 = (long)F_FRAMES * JC * CH;       // 7,962,624
  const long n2 = (long)MREAL * CH;               // 5,640,192
  const long n3 = (long)(M2 - MREAL) * K2;        // 143,360
  if (i < n1){
    long f = i / (JC*CH); long r = i % (JC*CH);
    int j = (int)(r >> 8); int c = (int)(r & 255);
    uint16_t v = 0;
    if (j < 17) v = x[(f*17 + j)*CH + c];
    xc0[i] = v;
  } else if (i < n1 + n2){
    long i2 = i - n1;
    long row = i2 >> 8; int c = (int)(i2 & 255);
    y[row*K2 + c] = x[i2];
  } else if (i < n1 + n2 + n3){
    long i3 = i - n1 - n2;
    long row = MREAL + i3 / K2; int c = (int)(i3 % K2);
    y[row*K2 + c] = 0;
  }
}

// ---------------- GEMM: C[M,N] = A[M,K] * B[N,K]^T, bf16 in, f32 accum --------
template<int OUT_F32>
__global__ __launch_bounds__(256) void gemm_bt(const uint16_t* __restrict__ A,
        const uint16_t* __restrict__ B, void* __restrict__ Cv,
        int M, int N, int K){
  __shared__ uint16_t As[128*64];
  __shared__ uint16_t Bs[128*64];
  int t = threadIdx.x;
  int lane = t & 63, w = t >> 6;
  int wr = (w >> 1) * 64, wc = (w & 1) * 64;
  long bm = (long)blockIdx.x * 128;
  long bn = (long)blockIdx.y * 128;
  f4v acc[4][4];
  #pragma unroll
  for (int i=0;i<4;i++){
    #pragma unroll
    for (int jq=0;jq<4;jq++) acc[i][jq] = (f4v){0.f,0.f,0.f,0.f};
  }
  const int nk = K >> 6;
  for (int kt = 0; kt < nk; ++kt){
    const uint16_t* Ag = A + bm * K + kt*64;
    const uint16_t* Bg = B + bn * K + kt*64;
    #pragma unroll
    for (int i=0;i<4;i++){
      int flat = i*256 + t;
      int row = flat >> 3, col = (flat & 7) << 3;
      __builtin_amdgcn_global_load_lds(
        (const GLOBAL_AS void*)(Ag + (long)row*K + col),
        (LDS_AS void*)(As + flat*8), 16, 0, 0);
    }
    #pragma unroll
    for (int i=0;i<4;i++){
      int flat = i*256 + t;
      int row = flat >> 3, col = (flat & 7) << 3;
      __builtin_amdgcn_global_load_lds(
        (const GLOBAL_AS void*)(Bg + (long)row*K + col),
        (LDS_AS void*)(Bs + flat*8), 16, 0, 0);
    }
    __syncthreads();
    #pragma unroll
    for (int kk=0; kk<2; ++kk){
      s8v af[4], bfr[4];
      int kof = kk*32 + (lane>>4)*8;
      #pragma unroll
      for (int mi=0;mi<4;mi++)
        af[mi] = *(const s8v*)(As + (wr + mi*16 + (lane&15))*64 + kof);
      #pragma unroll
      for (int ni=0;ni<4;ni++)
        bfr[ni] = *(const s8v*)(Bs + (wc + ni*16 + (lane&15))*64 + kof);
      #pragma unroll
      for (int mi=0;mi<4;mi++){
        #pragma unroll
        for (int ni=0;ni<4;ni++)
          acc[mi][ni] = __builtin_amdgcn_mfma_f32_16x16x32_bf16(af[mi], bfr[ni], acc[mi][ni], 0,0,0);
      }
    }
    __syncthreads();
  }
  #pragma unroll
  for (int mi=0;mi<4;mi++){
    #pragma unroll
    for (int ni=0;ni<4;ni++){
      long col = bn + wc + ni*16 + (lane & 15);
      #pragma unroll
      for (int r=0;r<4;r++){
        long row = bm + wr + mi*16 + (lane>>4)*4 + r;
        if (OUT_F32) ((float*)Cv)[row*N + col] = acc[mi][ni][r];
        else ((uint16_t*)Cv)[row*N + col] = f2b(acc[mi][ni][r]);
      }
    }
  }
}

// ---------------- GAT + LN (one frame per block) ------------------------------
__global__ __launch_bounds__(256) void gat_kernel(
    const uint16_t* __restrict__ qkv, const uint16_t* __restrict__ xc,
    const int* __restrict__ edges, const uint16_t* __restrict__ aw,
    const uint16_t* __restrict__ gw, const uint16_t* __restrict__ bw,
    uint16_t* __restrict__ xc_out, uint16_t* __restrict__ y,
    int E, int ycol)
{
  __shared__ uint16_t qs[JC*NH*128];   // q|k per (j,h): 49,152 B
  __shared__ float s_ex[EMAX*NH];
  __shared__ float smax[NH];
  __shared__ float awf[64];
  __shared__ int esrc[EMAX], edst[EMAX];
  __shared__ float gl[CH], bl[CH];

  int f = blockIdx.x;
  int t = threadIdx.x;
  const uint16_t* qg = qkv + (long)f * JC * N1;

  // stage q|k slices: 3072 16B chunks
  #pragma unroll
  for (int i=0;i<12;i++){
    int c = i*256 + t;
    int j = c >> 7; int rem = c & 127; int h = rem >> 4; int part = rem & 15;
    const uint16_t* src = qg + j*N1 + h*192 + part*8;
    __builtin_amdgcn_global_load_lds(
      (const GLOBAL_AS void*)src,
      (LDS_AS void*)(qs + c*8), 16, 0, 0);
  }
  if (t < E){ esrc[t] = edges[t]; edst[t] = edges[E + t]; }
  if (t < 64) awf[t] = b2f(aw[t]);
  gl[t] = b2f(gw[t]); bl[t] = b2f(bw[t]);
  __syncthreads();

  // edge logits s = <softplus(q[src]+k[dst]), a>
  for (int idx = t; idx < E*NH; idx += 256){
    int e = idx >> 3, h = idx & 7;
    const uint16_t* qp = qs + (esrc[e]*NH + h)*128;
    const uint16_t* kp = qs + (edst[e]*NH + h)*128 + 64;
    float s = 0.f;
    #pragma unroll
    for (int a0=0;a0<64;a0+=8){
      s8v qv = *(const s8v*)(qp + a0);
      s8v kv = *(const s8v*)(kp + a0);
      #pragma unroll
      for (int u=0;u<8;u++){
        float xv = b2f((uint16_t)qv[u]) + b2f((uint16_t)kv[u]);
        float z = fmaxf(xv, 0.f) + log1pf(expf(-fabsf(xv)));
        s += z * awf[a0+u];
      }
    }
    s_ex[idx] = s;
  }
  __syncthreads();
  if (t < NH){
    float m = -3.4e38f;
    for (int e=0;e<E;e++) m = fmaxf(m, s_ex[e*8 + t]);
    smax[t] = m;
  }
  __syncthreads();
  for (int idx = t; idx < E*NH; idx += 256)
    s_ex[idx] = expf(s_ex[idx] - smax[idx & 7]);
  __syncthreads();

  if (t < JC*NH){
    int j = t >> 3, h = t & 7;
    uint64_t mlo = 0, mhi = 0;
    for (int e=0;e<E;e++){
      if (esrc[e]==j){ if (e<64) mlo |= (1ull<<e); else mhi |= (1ull<<(e-64)); }
    }
    float sig = 1e-10f;
    { uint64_t m = mlo; while(m){ int e = __builtin_ctzll(m); m &= m-1; sig += s_ex[e*8+h]; }
      m = mhi;          while(m){ int e = 64 + __builtin_ctzll(m); m &= m-1; sig += s_ex[e*8+h]; } }
    float inv = 1.f / sig;
    float acc[32];
    #pragma unroll
    for (int d=0;d<32;d++) acc[d] = 0.f;
    auto agg_edge = [&](int e){
      float wgt = s_ex[e*8+h] * inv;
      const uint16_t* vp = qg + edst[e]*N1 + h*192 + 160;
      #pragma unroll
      for (int d0=0; d0<32; d0+=8){
        s8v v = *(const s8v*)(vp + d0);
        #pragma unroll
        for (int u=0;u<8;u++) acc[d0+u] += wgt * b2f((uint16_t)v[u]);
      }
    };
    { uint64_t m = mlo; while(m){ int e = __builtin_ctzll(m); m &= m-1; agg_edge(e); }
      m = mhi;          while(m){ int e = 64 + __builtin_ctzll(m); m &= m-1; agg_edge(e); } }

    const uint16_t* v1p = qg + j*N1 + h*192 + 128;
    const uint16_t* xp = xc + ((long)f*JC + j)*CH + h*32;
    float pre[32]; float sum = 0.f, sq = 0.f;
    #pragma unroll
    for (int d0=0; d0<32; d0+=8){
      s8v v1 = *(const s8v*)(v1p + d0);
      s8v xv = *(const s8v*)(xp + d0);
      #pragma unroll
      for (int u=0;u<8;u++){
        float p = b2f((uint16_t)xv[u]) + 0.2f*b2f((uint16_t)v1[u]) + 0.8f*acc[d0+u];
        pre[d0+u] = p; sum += p; sq += p*p;
      }
    }
    #pragma unroll
    for (int m=1;m<8;m<<=1){ sum += __shfl_xor(sum, m, 64); sq += __shfl_xor(sq, m, 64); }
    float mean = sum * (1.f/256.f);
    float var = sq * (1.f/256.f) - mean*mean;
    float rstd = rsqrtf(var + 1e-5f);
    uint16_t* xo = xc_out + ((long)f*JC + j)*CH + h*32;
    uint16_t* yo = (j < 17) ? (y + (long)(f*17 + j)*K2 + ycol + h*32) : (uint16_t*)0;
    #pragma unroll
    for (int d0=0; d0<32; d0+=8){
      s8v ov;
      #pragma unroll
      for (int u=0;u<8;u++){
        int c = h*32 + d0 + u;
        float val = (pre[d0+u]-mean)*rstd*gl[c] + bl[c];
        ov[u] = (short)f2b(val);
      }
      *(s8v*)(xo + d0) = ov;
      if (yo) *(s8v*)(yo + d0) = ov;
    }
  }
}

// ---------------- final bias + LN (output dtype selected by flag) ------------
__global__ __launch_bounds__(256) void final_ln(const float* __restrict__ pre,
    const uint16_t* __restrict__ pb, const uint16_t* __restrict__ gp,
    const uint16_t* __restrict__ bp, const int* __restrict__ flag,
    void* __restrict__ out){
  int row = blockIdx.x*4 + (threadIdx.x>>6);
  int lane = threadIdx.x & 63;
  const float* p = pre + (long)row*CH + lane*4;
  f4v pv = *(const f4v*)p;
  float v[4]; float sum = 0.f, sq = 0.f;
  #pragma unroll
  for (int i=0;i<4;i++){ int c = lane*4+i; v[i] = pv[i] + b2f(pb[c]); sum += v[i]; sq += v[i]*v[i]; }
  #pragma unroll
  for (int m=1;m<64;m<<=1){ sum += __shfl_xor(sum, m, 64); sq += __shfl_xor(sq, m, 64); }
  float mean = sum * (1.f/256.f);
  float var = sq * (1.f/256.f) - mean*mean;
  float rstd = rsqrtf(var + 1e-5f);
  float o[4];
  #pragma unroll
  for (int i=0;i<4;i++){
    int c = lane*4+i;
    o[i] = (v[i]-mean)*rstd*b2f(gp[c]) + b2f(bp[c]);
  }
  if (*flag){
    s4v ov;
    #pragma unroll
    for (int i=0;i<4;i++) ov[i] = (short)f2b(o[i]);
    *(s4v*)((uint16_t*)out + (long)row*CH + lane*4) = ov;
  } else {
    f4v ov;
    #pragma unroll
    for (int i=0;i<4;i++) ov[i] = o[i];
    *(f4v*)((float*)out + (long)row*CH + lane*4) = ov;
  }
}

// ---------------- launch ------------------------------------------------------
extern "C" void kernel_launch(void* const* d_in, const int* in_sizes, int n_in,
                              void* d_out, int out_size, void* d_ws, size_t ws_size,
                              hipStream_t stream){
  const int* eskel = (const int*)d_in[21];
  const int* ecay  = (const int*)d_in[22];

  char* ws = (char*)d_ws;
  const size_t QKV_B  = (size_t)M1 * N1 * 2;            // 95,551,488
  const size_t XC_B   = (size_t)M1 * CH * 2;            // 15,925,248
  const size_t Y_B    = (size_t)M2 * K2 * 2;            // 56,688,640
  const size_t ARENA_OFF = QKV_B + 2*XC_B + Y_B;        // 184,090,624
  const size_t ARENA_B = 7543808L * 2;                  // 15,087,616
  uint16_t* qkv = (uint16_t*)ws;
  float*    pre = (float*)ws;                           // reuses qkv region
  uint16_t* xcA = (uint16_t*)(ws + QKV_B);
  uint16_t* xcB = (uint16_t*)(ws + QKV_B + XC_B);
  uint16_t* y   = (uint16_t*)(ws + QKV_B + 2*XC_B);
  uint16_t* arena = (uint16_t*)(ws + ARENA_OFF);
  int*      flag  = (int*)(ws + ARENA_OFF + ARENA_B);

  const uint16_t* x_bf = arena;
  const uint16_t* wq[4] = {arena + 5640192, arena + 6033984, arena + 6427776, arena + 6821568};
  const uint16_t* aw[4] = {arena + 6033408, arena + 6427200, arena + 6820992, arena + 7214784};
  const uint16_t* gg[4] = {arena + 6033472, arena + 6427264, arena + 6821056, arena + 7214848};
  const uint16_t* bb[4] = {arena + 6033728, arena + 6427520, arena + 6821312, arena + 7215104};
  const uint16_t* pw = arena + 7215360;
  const uint16_t* pb = arena + 7543040;
  const uint16_t* gp = arena + 7543296;
  const uint16_t* bp = arena + 7543552;

  detect_kernel<<<1, 256, 0, stream>>>((const uint16_t*)d_in[0], flag);

  Ptrs ptrs;
  for (int i = 0; i < 21; i++) ptrs.p[i] = d_in[i];
  convert_kernel<<<3684, 256, 0, stream>>>(ptrs, flag, arena);

  prep_kernel<<<53696, 256, 0, stream>>>(x_bf, xcA, y);

  uint16_t* xcs[2] = {xcA, xcB};
  for (int L = 0; L < 4; ++L){
    gemm_bt<0><<<dim3(243, 12), 256, 0, stream>>>(xcs[L & 1], wq[L], qkv, M1, N1, K1);
    const int* ed = (L & 1) ? ecay : eskel;
    int E = (L & 1) ? 120 : 49;
    gat_kernel<<<F_FRAMES, 256, 0, stream>>>(qkv, xcs[L & 1], ed, aw[L], gg[L], bb[L],
                                             xcs[(L + 1) & 1], y, E, (L + 1) * 256);
  }
  gemm_bt<1><<<dim3(173, 2), 256, 0, stream>>>(y, pw, pre, M2, N2, K2);
  final_ln<<<5508, 256, 0, stream>>>(pre, pb, gp, bp, flag, d_out);
}

// Round 3
// 636.626 us; speedup vs baseline: 1.9639x; 1.9639x over previous
//
#include <hip/hip_runtime.h>
#include <stdint.h>

#define F_FRAMES 1296
#define JC 24
#define CH 256
#define NH 8
#define EMAX 120
#define M1 31104
#define N1 1536
#define K1 256
#define M2 22144
#define MREAL 22032
#define K2 1280
#define N2 256

typedef __attribute__((ext_vector_type(8))) short s8v;
typedef __attribute__((ext_vector_type(4))) short s4v;
typedef __attribute__((ext_vector_type(4))) float f4v;

#define GLOBAL_AS __attribute__((address_space(1)))
#define LDS_AS __attribute__((address_space(3)))

__device__ __forceinline__ float b2f(uint16_t u){
  union { float f; uint32_t u; } v; v.u = ((uint32_t)u) << 16; return v.f;
}
__device__ __forceinline__ uint16_t f2b(float f){
  union { float f; uint32_t u; } v; v.f = f;
  uint32_t u = v.u;
  uint32_t r = (u + 0x7fffu + ((u >> 16) & 1u)) >> 16;
  return (uint16_t)r;
}

// ---------------- dtype detection -------------------------------------------
__global__ __launch_bounds__(256) void detect_kernel(const uint16_t* __restrict__ x,
                                                     int* __restrict__ flag){
  __shared__ int cnt;
  if (threadIdx.x == 0) cnt = 0;
  __syncthreads();
  int good = 0;
  for (int i = threadIdx.x; i < 512; i += 256){
    uint16_t v = x[i];
    int e = (v >> 7) & 0xFF;
    good += (e >= 115 && e <= 131) ? 1 : 0;
  }
  atomicAdd(&cnt, good);
  __syncthreads();
  if (threadIdx.x == 0) *flag = (cnt >= 400) ? 1 : 0;
}

// ---------------- convert all float inputs into a bf16 arena ----------------
struct Ptrs { const void* p[21]; };

__constant__ int c_off[22] = {
  0, 5640192, 6033408, 6033472, 6033728, 6033984, 6427200, 6427264, 6427520,
  6427776, 6820992, 6821056, 6821312, 6821568, 7214784, 7214848, 7215104,
  7215360, 7543040, 7543296, 7543552, 7543808};

__global__ __launch_bounds__(256) void convert_kernel(Ptrs ptrs,
        const int* __restrict__ flag, uint16_t* __restrict__ arena){
  long base = ((long)blockIdx.x * 256 + threadIdx.x) * 8;
  if (base >= 7543808L) return;
  int seg = 0;
  while (c_off[seg + 1] <= base) seg++;
  long loc = base - c_off[seg];
  if (*flag){
    *(s8v*)(arena + base) = *(const s8v*)((const uint16_t*)ptrs.p[seg] + loc);
  } else {
    const float* s = (const float*)ptrs.p[seg] + loc;
    f4v a = *(const f4v*)s;
    f4v b = *(const f4v*)(s + 4);
    s8v o;
    #pragma unroll
    for (int u = 0; u < 4; u++){ o[u] = (short)f2b(a[u]); o[4+u] = (short)f2b(b[u]); }
    *(s8v*)(arena + base) = o;
  }
}

// ---------------- prep ---------------------------------------------------------
__global__ __launch_bounds__(256) void prep_kernel(const uint16_t* __restrict__ x,
                     uint16_t* __restrict__ xc0, uint16_t* __restrict__ y){
  long i = (long)blockIdx.x * 256 + threadIdx.x;
  const long n1 = (long)F_FRAMES * JC * CH;
  const long n2 = (long)MREAL * CH;
  const long n3 = (long)(M2 - MREAL) * K2;
  if (i < n1){
    long f = i / (JC*CH); long r = i % (JC*CH);
    int j = (int)(r >> 8); int c = (int)(r & 255);
    uint16_t v = 0;
    if (j < 17) v = x[(f*17 + j)*CH + c];
    xc0[i] = v;
  } else if (i < n1 + n2){
    long i2 = i - n1;
    long row = i2 >> 8; int c = (int)(i2 & 255);
    y[row*K2 + c] = x[i2];
  } else if (i < n1 + n2 + n3){
    long i3 = i - n1 - n2;
    long row = MREAL + i3 / K2; int c = (int)(i3 % K2);
    y[row*K2 + c] = 0;
  }
}

// ---------------- GEMM (unchanged, proven) -----------------------------------
template<int OUT_F32>
__global__ __launch_bounds__(256) void gemm_bt(const uint16_t* __restrict__ A,
        const uint16_t* __restrict__ B, void* __restrict__ Cv,
        int M, int N, int K){
  __shared__ uint16_t As[128*64];
  __shared__ uint16_t Bs[128*64];
  int t = threadIdx.x;
  int lane = t & 63, w = t >> 6;
  int wr = (w >> 1) * 64, wc = (w & 1) * 64;
  long bm = (long)blockIdx.x * 128;
  long bn = (long)blockIdx.y * 128;
  f4v acc[4][4];
  #pragma unroll
  for (int i=0;i<4;i++){
    #pragma unroll
    for (int jq=0;jq<4;jq++) acc[i][jq] = (f4v){0.f,0.f,0.f,0.f};
  }
  const int nk = K >> 6;
  for (int kt = 0; kt < nk; ++kt){
    const uint16_t* Ag = A + bm * K + kt*64;
    const uint16_t* Bg = B + bn * K + kt*64;
    #pragma unroll
    for (int i=0;i<4;i++){
      int flat = i*256 + t;
      int row = flat >> 3, col = (flat & 7) << 3;
      __builtin_amdgcn_global_load_lds(
        (const GLOBAL_AS void*)(Ag + (long)row*K + col),
        (LDS_AS void*)(As + flat*8), 16, 0, 0);
    }
    #pragma unroll
    for (int i=0;i<4;i++){
      int flat = i*256 + t;
      int row = flat >> 3, col = (flat & 7) << 3;
      __builtin_amdgcn_global_load_lds(
        (const GLOBAL_AS void*)(Bg + (long)row*K + col),
        (LDS_AS void*)(Bs + flat*8), 16, 0, 0);
    }
    __syncthreads();
    #pragma unroll
    for (int kk=0; kk<2; ++kk){
      s8v af[4], bfr[4];
      int kof = kk*32 + (lane>>4)*8;
      #pragma unroll
      for (int mi=0;mi<4;mi++)
        af[mi] = *(const s8v*)(As + (wr + mi*16 + (lane&15))*64 + kof);
      #pragma unroll
      for (int ni=0;ni<4;ni++)
        bfr[ni] = *(const s8v*)(Bs + (wc + ni*16 + (lane&15))*64 + kof);
      #pragma unroll
      for (int mi=0;mi<4;mi++){
        #pragma unroll
        for (int ni=0;ni<4;ni++)
          acc[mi][ni] = __builtin_amdgcn_mfma_f32_16x16x32_bf16(af[mi], bfr[ni], acc[mi][ni], 0,0,0);
      }
    }
    __syncthreads();
  }
  #pragma unroll
  for (int mi=0;mi<4;mi++){
    #pragma unroll
    for (int ni=0;ni<4;ni++){
      long col = bn + wc + ni*16 + (lane & 15);
      #pragma unroll
      for (int r=0;r<4;r++){
        long row = bm + wr + mi*16 + (lane>>4)*4 + r;
        if (OUT_F32) ((float*)Cv)[row*N + col] = acc[mi][ni][r];
        else ((uint16_t*)Cv)[row*N + col] = f2b(acc[mi][ni][r]);
      }
    }
  }
}

// ---------------- GAT + LN (rewritten: parallel phases, fast softplus) --------
__global__ __launch_bounds__(256) void gat_kernel(
    const uint16_t* __restrict__ qkv, const uint16_t* __restrict__ xc,
    const int* __restrict__ edges, const uint16_t* __restrict__ aw,
    const uint16_t* __restrict__ gw, const uint16_t* __restrict__ bw,
    uint16_t* __restrict__ xc_out, uint16_t* __restrict__ y,
    int E, int ycol)
{
  __shared__ uint16_t qs[JC*NH*128];       // swizzled q|k rows, 49152 B
  __shared__ float s_ex[EMAX*NH];          // raw logits
  __shared__ float smax[NH];
  __shared__ float awf[64];
  __shared__ int esrc[EMAX], edst[EMAX];
  __shared__ int ecnt[JC];
  __shared__ int elist[JC][8];
  __shared__ float gl[CH], bl[CH];

  int f = blockIdx.x;
  int t = threadIdx.x;
  const uint16_t* qg = qkv + (long)f * JC * N1;

  // stage q|k with XOR-swizzled SOURCE (LDS dest linear; reader XORs chunk by h)
  #pragma unroll
  for (int i=0;i<12;i++){
    int c = i*256 + t;            // 16B granule id, 0..3071
    int row = c >> 4;             // j*8+h
    int j = row >> 3, h = row & 7;
    int ch = c & 15;
    int chp = (ch & 8) | ((ch & 7) ^ h);     // logical chunk stored here
    const uint16_t* src = qg + j*N1 + h*192 +
                          ((chp & 8) ? (64 + (chp & 7)*8) : (chp*8));
    __builtin_amdgcn_global_load_lds(
      (const GLOBAL_AS void*)src,
      (LDS_AS void*)(qs + c*8), 16, 0, 0);
  }
  if (t < E){ esrc[t] = edges[t]; edst[t] = edges[E + t]; }
  if (t < 64) awf[t] = b2f(aw[t]);
  gl[t] = b2f(gw[t]); bl[t] = b2f(bw[t]);
  __syncthreads();

  // per-thread a-weight slice (ln = t&7 fixed): a and ln2*a
  float areg[8], aregc[8];
  {
    int ln = t & 7;
    #pragma unroll
    for (int u=0;u<8;u++){
      areg[u] = awf[ln*8 + u];
      aregc[u] = areg[u] * 0.69314718056f;
    }
  }

  // Phase A: edge logits. 8 lanes per (e,h); each lane 8 dims; shfl-reduce.
  const int EN = E * NH;
  for (int base = 0; base < EN*8; base += 256){
    int slot = base + t;
    int item = slot >> 3;
    int ln = slot & 7;
    float s = 0.f;
    if (item < EN){
      int e = item >> 3, h = item & 7;
      int cs = ln ^ h;
      const uint16_t* qp = qs + ((esrc[e]*8 + h)*16 + cs)*8;
      const uint16_t* kp = qs + ((edst[e]*8 + h)*16 + 8 + cs)*8;
      s8v qv = *(const s8v*)qp;
      s8v kv = *(const s8v*)kp;
      #pragma unroll
      for (int u=0;u<8;u++){
        float xv = b2f((uint16_t)qv[u]) + b2f((uint16_t)kv[u]);
        float e2 = exp2f(fabsf(xv) * -1.44269504f);
        float lg = log2f(1.f + e2);
        s = fmaxf(xv, 0.f) * areg[u] + s;
        s = lg * aregc[u] + s;
      }
    }
    s += __shfl_xor(s, 1, 64);
    s += __shfl_xor(s, 2, 64);
    s += __shfl_xor(s, 4, 64);
    if (item < EN && ln == 0) s_ex[item] = s;
  }
  __syncthreads();

  // smax per head (wave 0) + per-src edge lists (wave 1) in parallel
  if (t < 8){
    float m = -3.4e38f;
    for (int e=0;e<E;e++) m = fmaxf(m, s_ex[e*8 + t]);
    smax[t] = m;
  }
  if (t >= 64 && t < 64 + JC){
    int j = t - 64;
    int c = 0;
    for (int e=0;e<E;e++) if (esrc[e] == j) elist[j][c++] = e;
    ecnt[j] = c;
  }
  __syncthreads();

  // Phase B: per (j,h): segment softmax + aggregation + residual + LN
  if (t < JC*NH){
    int j = t >> 3, h = t & 7;
    int deg = ecnt[j];
    float mh = smax[h];
    float sig = 1e-10f;
    for (int i=0;i<deg;i++){
      int e = elist[j][i];
      sig += exp2f((s_ex[e*8+h] - mh) * 1.44269504f);
    }
    float inv = 1.f / sig;
    float acc[32];
    #pragma unroll
    for (int d=0;d<32;d++) acc[d] = 0.f;
    for (int i=0;i<deg;i++){
      int e = elist[j][i];
      float wgt = exp2f((s_ex[e*8+h] - mh) * 1.44269504f) * inv;
      const uint16_t* vp = qg + edst[e]*N1 + h*192 + 160;
      #pragma unroll
      for (int d0=0; d0<32; d0+=8){
        s8v v = *(const s8v*)(vp + d0);
        #pragma unroll
        for (int u=0;u<8;u++) acc[d0+u] += wgt * b2f((uint16_t)v[u]);
      }
    }

    const uint16_t* v1p = qg + j*N1 + h*192 + 128;
    const uint16_t* xp = xc + ((long)f*JC + j)*CH + h*32;
    float pre[32]; float sum = 0.f, sq = 0.f;
    #pragma unroll
    for (int d0=0; d0<32; d0+=8){
      s8v v1 = *(const s8v*)(v1p + d0);
      s8v xv = *(const s8v*)(xp + d0);
      #pragma unroll
      for (int u=0;u<8;u++){
        float p = b2f((uint16_t)xv[u]) + 0.2f*b2f((uint16_t)v1[u]) + 0.8f*acc[d0+u];
        pre[d0+u] = p; sum += p; sq += p*p;
      }
    }
    #pragma unroll
    for (int m=1;m<8;m<<=1){ sum += __shfl_xor(sum, m, 64); sq += __shfl_xor(sq, m, 64); }
    float mean = sum * (1.f/256.f);
    float var = sq * (1.f/256.f) - mean*mean;
    float rstd = rsqrtf(var + 1e-5f);
    uint16_t* xo = xc_out + ((long)f*JC + j)*CH + h*32;
    uint16_t* yo = (j < 17) ? (y + (long)(f*17 + j)*K2 + ycol + h*32) : (uint16_t*)0;
    #pragma unroll
    for (int d0=0; d0<32; d0+=8){
      s8v ov;
      #pragma unroll
      for (int u=0;u<8;u++){
        int c = h*32 + d0 + u;
        float val = (pre[d0+u]-mean)*rstd*gl[c] + bl[c];
        ov[u] = (short)f2b(val);
      }
      *(s8v*)(xo + d0) = ov;
      if (yo) *(s8v*)(yo + d0) = ov;
    }
  }
}

// ---------------- final bias + LN --------------------------------------------
__global__ __launch_bounds__(256) void final_ln(const float* __restrict__ pre,
    const uint16_t* __restrict__ pb, const uint16_t* __restrict__ gp,
    const uint16_t* __restrict__ bp, const int* __restrict__ flag,
    void* __restrict__ out){
  int row = blockIdx.x*4 + (threadIdx.x>>6);
  int lane = threadIdx.x & 63;
  const float* p = pre + (long)row*CH + lane*4;
  f4v pv = *(const f4v*)p;
  float v[4]; float sum = 0.f, sq = 0.f;
  #pragma unroll
  for (int i=0;i<4;i++){ int c = lane*4+i; v[i] = pv[i] + b2f(pb[c]); sum += v[i]; sq += v[i]*v[i]; }
  #pragma unroll
  for (int m=1;m<64;m<<=1){ sum += __shfl_xor(sum, m, 64); sq += __shfl_xor(sq, m, 64); }
  float mean = sum * (1.f/256.f);
  float var = sq * (1.f/256.f) - mean*mean;
  float rstd = rsqrtf(var + 1e-5f);
  float o[4];
  #pragma unroll
  for (int i=0;i<4;i++){
    int c = lane*4+i;
    o[i] = (v[i]-mean)*rstd*b2f(gp[c]) + b2f(bp[c]);
  }
  if (*flag){
    s4v ov;
    #pragma unroll
    for (int i=0;i<4;i++) ov[i] = (short)f2b(o[i]);
    *(s4v*)((uint16_t*)out + (long)row*CH + lane*4) = ov;
  } else {
    f4v ov;
    #pragma unroll
    for (int i=0;i<4;i++) ov[i] = o[i];
    *(f4v*)((float*)out + (long)row*CH + lane*4) = ov;
  }
}

// ---------------- launch ------------------------------------------------------
extern "C" void kernel_launch(void* const* d_in, const int* in_sizes, int n_in,
                              void* d_out, int out_size, void* d_ws, size_t ws_size,
                              hipStream_t stream){
  const int* eskel = (const int*)d_in[21];
  const int* ecay  = (const int*)d_in[22];

  char* ws = (char*)d_ws;
  const size_t QKV_B  = (size_t)M1 * N1 * 2;
  const size_t XC_B   = (size_t)M1 * CH * 2;
  const size_t Y_B    = (size_t)M2 * K2 * 2;
  const size_t ARENA_OFF = QKV_B + 2*XC_B + Y_B;
  const size_t ARENA_B = 7543808L * 2;
  uint16_t* qkv = (uint16_t*)ws;
  float*    pre = (float*)ws;
  uint16_t* xcA = (uint16_t*)(ws + QKV_B);
  uint16_t* xcB = (uint16_t*)(ws + QKV_B + XC_B);
  uint16_t* y   = (uint16_t*)(ws + QKV_B + 2*XC_B);
  uint16_t* arena = (uint16_t*)(ws + ARENA_OFF);
  int*      flag  = (int*)(ws + ARENA_OFF + ARENA_B);

  const uint16_t* x_bf = arena;
  const uint16_t* wq[4] = {arena + 5640192, arena + 6033984, arena + 6427776, arena + 6821568};
  const uint16_t* aw[4] = {arena + 6033408, arena + 6427200, arena + 6820992, arena + 7214784};
  const uint16_t* gg[4] = {arena + 6033472, arena + 6427264, arena + 6821056, arena + 7214848};
  const uint16_t* bb[4] = {arena + 6033728, arena + 6427520, arena + 6821312, arena + 7215104};
  const uint16_t* pw = arena + 7215360;
  const uint16_t* pb = arena + 7543040;
  const uint16_t* gp = arena + 7543296;
  const uint16_t* bp = arena + 7543552;

  detect_kernel<<<1, 256, 0, stream>>>((const uint16_t*)d_in[0], flag);

  Ptrs ptrs;
  for (int i = 0; i < 21; i++) ptrs.p[i] = d_in[i];
  convert_kernel<<<3684, 256, 0, stream>>>(ptrs, flag, arena);

  prep_kernel<<<53696, 256, 0, stream>>>(x_bf, xcA, y);

  uint16_t* xcs[2] = {xcA, xcB};
  for (int L = 0; L < 4; ++L){
    gemm_bt<0><<<dim3(243, 12), 256, 0, stream>>>(xcs[L & 1], wq[L], qkv, M1, N1, K1);
    const int* ed = (L & 1) ? ecay : eskel;
    int E = (L & 1) ? 120 : 49;
    gat_kernel<<<F_FRAMES, 256, 0, stream>>>(qkv, xcs[L & 1], ed, aw[L], gg[L], bb[L],
                                             xcs[(L + 1) & 1], y, E, (L + 1) * 256);
  }
  gemm_bt<1><<<dim3(173, 2), 256, 0, stream>>>(y, pw, pre, M2, N2, K2);
  final_ln<<<5508, 256, 0, stream>>>(pre, pb, gp, bp, flag, d_out);
}

// Round 4
// 556.393 us; speedup vs baseline: 2.2471x; 1.1442x over previous
//
#include <hip/hip_runtime.h>
#include <stdint.h>

#define F_FRAMES 1296
#define JC 24
#define CH 256
#define NH 8
#define EMAX 120
#define M1 31104
#define N1 1536
#define K1 256
#define M2 22144
#define MREAL 22032
#define K2 1280
#define N2 256

typedef __attribute__((ext_vector_type(8))) short s8v;
typedef __attribute__((ext_vector_type(4))) short s4v;
typedef __attribute__((ext_vector_type(4))) float f4v;

#define GLOBAL_AS __attribute__((address_space(1)))
#define LDS_AS __attribute__((address_space(3)))

__device__ __forceinline__ float b2f(uint16_t u){
  union { float f; uint32_t u; } v; v.u = ((uint32_t)u) << 16; return v.f;
}
__device__ __forceinline__ uint16_t f2b(float f){
  union { float f; uint32_t u; } v; v.f = f;
  uint32_t u = v.u;
  uint32_t r = (u + 0x7fffu + ((u >> 16) & 1u)) >> 16;
  return (uint16_t)r;
}

// ---------------- dtype detection -------------------------------------------
__global__ __launch_bounds__(256) void detect_kernel(const uint16_t* __restrict__ x,
                                                     int* __restrict__ flag){
  __shared__ int cnt;
  if (threadIdx.x == 0) cnt = 0;
  __syncthreads();
  int good = 0;
  for (int i = threadIdx.x; i < 512; i += 256){
    uint16_t v = x[i];
    int e = (v >> 7) & 0xFF;
    good += (e >= 115 && e <= 131) ? 1 : 0;
  }
  atomicAdd(&cnt, good);
  __syncthreads();
  if (threadIdx.x == 0) *flag = (cnt >= 400) ? 1 : 0;
}

// ---------------- convert all float inputs into a bf16 arena ----------------
struct Ptrs { const void* p[21]; };

__constant__ int c_off[22] = {
  0, 5640192, 6033408, 6033472, 6033728, 6033984, 6427200, 6427264, 6427520,
  6427776, 6820992, 6821056, 6821312, 6821568, 7214784, 7214848, 7215104,
  7215360, 7543040, 7543296, 7543552, 7543808};

__global__ __launch_bounds__(256) void convert_kernel(Ptrs ptrs,
        const int* __restrict__ flag, uint16_t* __restrict__ arena){
  long base = ((long)blockIdx.x * 256 + threadIdx.x) * 8;
  if (base >= 7543808L) return;
  int seg = 0;
  while (c_off[seg + 1] <= base) seg++;
  long loc = base - c_off[seg];
  if (*flag){
    *(s8v*)(arena + base) = *(const s8v*)((const uint16_t*)ptrs.p[seg] + loc);
  } else {
    const float* s = (const float*)ptrs.p[seg] + loc;
    f4v a = *(const f4v*)s;
    f4v b = *(const f4v*)(s + 4);
    s8v o;
    #pragma unroll
    for (int u = 0; u < 4; u++){ o[u] = (short)f2b(a[u]); o[4+u] = (short)f2b(b[u]); }
    *(s8v*)(arena + base) = o;
  }
}

// ---------------- prep ---------------------------------------------------------
__global__ __launch_bounds__(256) void prep_kernel(const uint16_t* __restrict__ x,
                     uint16_t* __restrict__ xc0, uint16_t* __restrict__ y){
  long i = (long)blockIdx.x * 256 + threadIdx.x;
  const long n1 = (long)F_FRAMES * JC * CH;
  const long n2 = (long)MREAL * CH;
  const long n3 = (long)(M2 - MREAL) * K2;
  if (i < n1){
    long f = i / (JC*CH); long r = i % (JC*CH);
    int j = (int)(r >> 8); int c = (int)(r & 255);
    uint16_t v = 0;
    if (j < 17) v = x[(f*17 + j)*CH + c];
    xc0[i] = v;
  } else if (i < n1 + n2){
    long i2 = i - n1;
    long row = i2 >> 8; int c = (int)(i2 & 255);
    y[row*K2 + c] = x[i2];
  } else if (i < n1 + n2 + n3){
    long i3 = i - n1 - n2;
    long row = MREAL + i3 / K2; int c = (int)(i3 % K2);
    y[row*K2 + c] = 0;
  }
}

// ---------------- GEMM (unchanged, proven) -----------------------------------
template<int OUT_F32>
__global__ __launch_bounds__(256) void gemm_bt(const uint16_t* __restrict__ A,
        const uint16_t* __restrict__ B, void* __restrict__ Cv,
        int M, int N, int K){
  __shared__ uint16_t As[128*64];
  __shared__ uint16_t Bs[128*64];
  int t = threadIdx.x;
  int lane = t & 63, w = t >> 6;
  int wr = (w >> 1) * 64, wc = (w & 1) * 64;
  long bm = (long)blockIdx.x * 128;
  long bn = (long)blockIdx.y * 128;
  f4v acc[4][4];
  #pragma unroll
  for (int i=0;i<4;i++){
    #pragma unroll
    for (int jq=0;jq<4;jq++) acc[i][jq] = (f4v){0.f,0.f,0.f,0.f};
  }
  const int nk = K >> 6;
  for (int kt = 0; kt < nk; ++kt){
    const uint16_t* Ag = A + bm * K + kt*64;
    const uint16_t* Bg = B + bn * K + kt*64;
    #pragma unroll
    for (int i=0;i<4;i++){
      int flat = i*256 + t;
      int row = flat >> 3, col = (flat & 7) << 3;
      __builtin_amdgcn_global_load_lds(
        (const GLOBAL_AS void*)(Ag + (long)row*K + col),
        (LDS_AS void*)(As + flat*8), 16, 0, 0);
    }
    #pragma unroll
    for (int i=0;i<4;i++){
      int flat = i*256 + t;
      int row = flat >> 3, col = (flat & 7) << 3;
      __builtin_amdgcn_global_load_lds(
        (const GLOBAL_AS void*)(Bg + (long)row*K + col),
        (LDS_AS void*)(Bs + flat*8), 16, 0, 0);
    }
    __syncthreads();
    #pragma unroll
    for (int kk=0; kk<2; ++kk){
      s8v af[4], bfr[4];
      int kof = kk*32 + (lane>>4)*8;
      #pragma unroll
      for (int mi=0;mi<4;mi++)
        af[mi] = *(const s8v*)(As + (wr + mi*16 + (lane&15))*64 + kof);
      #pragma unroll
      for (int ni=0;ni<4;ni++)
        bfr[ni] = *(const s8v*)(Bs + (wc + ni*16 + (lane&15))*64 + kof);
      #pragma unroll
      for (int mi=0;mi<4;mi++){
        #pragma unroll
        for (int ni=0;ni<4;ni++)
          acc[mi][ni] = __builtin_amdgcn_mfma_f32_16x16x32_bf16(af[mi], bfr[ni], acc[mi][ni], 0,0,0);
      }
    }
    __syncthreads();
  }
  #pragma unroll
  for (int mi=0;mi<4;mi++){
    #pragma unroll
    for (int ni=0;ni<4;ni++){
      long col = bn + wc + ni*16 + (lane & 15);
      #pragma unroll
      for (int r=0;r<4;r++){
        long row = bm + wr + mi*16 + (lane>>4)*4 + r;
        if (OUT_F32) ((float*)Cv)[row*N + col] = acc[mi][ni][r];
        else ((uint16_t*)Cv)[row*N + col] = f2b(acc[mi][ni][r]);
      }
    }
  }
}

// ---------------- GAT + LN v3: small LDS (v1/v2 staged), q/k from L2 ----------
// v1s/v2s layout: 192 rows (j*8+h) x 4 chunks of 16B; chunk c stored at
// c ^ ((row>>1)&3)  -> 8-lane read groups tile all 32 banks.
__global__ __launch_bounds__(256) void gat_kernel(
    const uint16_t* __restrict__ qkv, const uint16_t* __restrict__ xc,
    const int* __restrict__ edges, const uint16_t* __restrict__ aw,
    const uint16_t* __restrict__ gw, const uint16_t* __restrict__ bw,
    uint16_t* __restrict__ xc_out, uint16_t* __restrict__ y,
    int E, int ycol)
{
  __shared__ uint16_t v2s[JC*NH*32];   // 12288 B
  __shared__ uint16_t v1s[JC*NH*32];   // 12288 B
  __shared__ float s_ex[EMAX*NH];      // 3840 B
  __shared__ float smax[NH];
  __shared__ float awf[64];
  __shared__ int esrc[EMAX], edst[EMAX];
  __shared__ int ecnt[JC];
  __shared__ int elist[JC][8];
  __shared__ uint16_t glb[2*CH];       // gamma|beta bf16

  int f = blockIdx.x;
  int t = threadIdx.x;
  const uint16_t* qg = qkv + (long)f * JC * N1;

  // stage v2/v1: 768 granules each, LDS dest linear, source inverse-swizzled
  #pragma unroll
  for (int i=0;i<3;i++){
    int g = i*256 + t;
    int r = g >> 2, cs = g & 3;
    int c = cs ^ ((r >> 1) & 3);
    int j = r >> 3, h = r & 7;
    const uint16_t* s2 = qg + j*N1 + h*192 + 160 + c*8;
    __builtin_amdgcn_global_load_lds((const GLOBAL_AS void*)s2,
        (LDS_AS void*)(v2s + g*8), 16, 0, 0);
    const uint16_t* s1 = qg + j*N1 + h*192 + 128 + c*8;
    __builtin_amdgcn_global_load_lds((const GLOBAL_AS void*)s1,
        (LDS_AS void*)(v1s + g*8), 16, 0, 0);
  }
  if (t < E){ esrc[t] = edges[t]; edst[t] = edges[E + t]; }
  if (t < 64) awf[t] = b2f(aw[t]);
  glb[t] = gw[t]; glb[256 + t] = bw[t];
  __syncthreads();

  float areg[8], aregc[8];
  {
    int ln = t & 7;
    #pragma unroll
    for (int u=0;u<8;u++){
      areg[u] = awf[ln*8 + u];
      aregc[u] = areg[u] * 0.69314718056f;
    }
  }

  // Phase A: logits; 8 lanes per (e,h), q/k straight from global (L2)
  const int EN = E * NH;
  for (int base = 0; base < EN*8; base += 256){
    int slot = base + t;
    int item = slot >> 3;
    int ln = slot & 7;
    float s = 0.f;
    if (item < EN){
      int e = item >> 3, h = item & 7;
      const uint16_t* qp = qg + esrc[e]*N1 + h*192 + ln*8;
      const uint16_t* kp = qg + edst[e]*N1 + h*192 + 64 + ln*8;
      s8v qv = *(const s8v*)qp;
      s8v kv = *(const s8v*)kp;
      #pragma unroll
      for (int u=0;u<8;u++){
        float xv = b2f((uint16_t)qv[u]) + b2f((uint16_t)kv[u]);
        float e2 = exp2f(fabsf(xv) * -1.44269504f);
        float lg = log2f(1.f + e2);
        s = fmaxf(xv, 0.f) * areg[u] + s;
        s = lg * aregc[u] + s;
      }
    }
    s += __shfl_xor(s, 1, 64);
    s += __shfl_xor(s, 2, 64);
    s += __shfl_xor(s, 4, 64);
    if (item < EN && ln == 0) s_ex[item] = s;
  }
  __syncthreads();

  // smax per head: wave 0, 64 lanes (h = t&7, e strided by 8), shfl-reduce
  if (t < 64){
    int h = t & 7;
    float m = -3.4e38f;
    for (int e = t >> 3; e < E; e += 8) m = fmaxf(m, s_ex[e*8 + h]);
    m = fmaxf(m, __shfl_xor(m, 8, 64));
    m = fmaxf(m, __shfl_xor(m, 16, 64));
    m = fmaxf(m, __shfl_xor(m, 32, 64));
    if (t < 8) smax[t] = m;
  }
  // per-src edge lists: wave 1
  if (t >= 64 && t < 64 + JC){
    int j = t - 64;
    int c = 0;
    for (int e=0;e<E;e++) if (esrc[e] == j) elist[j][c++] = e;
    ecnt[j] = c;
  }
  __syncthreads();

  // Phase B: per (j,h) softmax + aggregate (LDS) + residual + LN
  if (t < JC*NH){
    int j = t >> 3, h = t & 7;
    int deg = ecnt[j];
    float mh = smax[h];
    float ex[8];
    float sig = 1e-10f;
    int el[8];
    #pragma unroll
    for (int i=0;i<8;i++){
      float v = 0.f; int e = 0;
      if (i < deg){ e = elist[j][i]; v = exp2f((s_ex[e*8+h] - mh) * 1.44269504f); }
      el[i] = e; ex[i] = v; sig += v;
    }
    float inv = 1.f / sig;
    float acc[32];
    #pragma unroll
    for (int d=0;d<32;d++) acc[d] = 0.f;
    #pragma unroll
    for (int i=0;i<8;i++){
      if (i < deg){
        float wgt = ex[i] * inv;
        int r = edst[el[i]]*8 + h;
        int sw = (r >> 1) & 3;
        #pragma unroll
        for (int c=0;c<4;c++){
          s8v v = *(const s8v*)(v2s + r*32 + (c ^ sw)*8);
          #pragma unroll
          for (int u=0;u<8;u++) acc[c*8+u] += wgt * b2f((uint16_t)v[u]);
        }
      }
    }

    int r1 = t;
    int sw1 = (r1 >> 1) & 3;
    const uint16_t* xp = xc + (long)f*JC*CH + t*32;
    float pre[32]; float sum = 0.f, sq = 0.f;
    #pragma unroll
    for (int c=0;c<4;c++){
      s8v v1 = *(const s8v*)(v1s + r1*32 + (c ^ sw1)*8);
      s8v xv = *(const s8v*)(xp + c*8);
      #pragma unroll
      for (int u=0;u<8;u++){
        float p = b2f((uint16_t)xv[u]) + 0.2f*b2f((uint16_t)v1[u]) + 0.8f*acc[c*8+u];
        pre[c*8+u] = p; sum += p; sq += p*p;
      }
    }
    #pragma unroll
    for (int m=1;m<8;m<<=1){ sum += __shfl_xor(sum, m, 64); sq += __shfl_xor(sq, m, 64); }
    float mean = sum * (1.f/256.f);
    float var = sq * (1.f/256.f) - mean*mean;
    float rstd = rsqrtf(var + 1e-5f);
    uint16_t* xo = xc_out + (long)f*JC*CH + t*32;
    uint16_t* yo = (j < 17) ? (y + (long)(f*17 + j)*K2 + ycol + h*32) : (uint16_t*)0;
    #pragma unroll
    for (int d0=0; d0<32; d0+=8){
      s8v ov;
      #pragma unroll
      for (int u=0;u<8;u++){
        int c = h*32 + d0 + u;
        float val = (pre[d0+u]-mean)*rstd*b2f(glb[c]) + b2f(glb[256+c]);
        ov[u] = (short)f2b(val);
      }
      *(s8v*)(xo + d0) = ov;
      if (yo) *(s8v*)(yo + d0) = ov;
    }
  }
}

// ---------------- final bias + LN --------------------------------------------
__global__ __launch_bounds__(256) void final_ln(const float* __restrict__ pre,
    const uint16_t* __restrict__ pb, const uint16_t* __restrict__ gp,
    const uint16_t* __restrict__ bp, const int* __restrict__ flag,
    void* __restrict__ out){
  int row = blockIdx.x*4 + (threadIdx.x>>6);
  int lane = threadIdx.x & 63;
  const float* p = pre + (long)row*CH + lane*4;
  f4v pv = *(const f4v*)p;
  float v[4]; float sum = 0.f, sq = 0.f;
  #pragma unroll
  for (int i=0;i<4;i++){ int c = lane*4+i; v[i] = pv[i] + b2f(pb[c]); sum += v[i]; sq += v[i]*v[i]; }
  #pragma unroll
  for (int m=1;m<64;m<<=1){ sum += __shfl_xor(sum, m, 64); sq += __shfl_xor(sq, m, 64); }
  float mean = sum * (1.f/256.f);
  float var = sq * (1.f/256.f) - mean*mean;
  float rstd = rsqrtf(var + 1e-5f);
  float o[4];
  #pragma unroll
  for (int i=0;i<4;i++){
    int c = lane*4+i;
    o[i] = (v[i]-mean)*rstd*b2f(gp[c]) + b2f(bp[c]);
  }
  if (*flag){
    s4v ov;
    #pragma unroll
    for (int i=0;i<4;i++) ov[i] = (short)f2b(o[i]);
    *(s4v*)((uint16_t*)out + (long)row*CH + lane*4) = ov;
  } else {
    f4v ov;
    #pragma unroll
    for (int i=0;i<4;i++) ov[i] = o[i];
    *(f4v*)((float*)out + (long)row*CH + lane*4) = ov;
  }
}

// ---------------- launch ------------------------------------------------------
extern "C" void kernel_launch(void* const* d_in, const int* in_sizes, int n_in,
                              void* d_out, int out_size, void* d_ws, size_t ws_size,
                              hipStream_t stream){
  const int* eskel = (const int*)d_in[21];
  const int* ecay  = (const int*)d_in[22];

  char* ws = (char*)d_ws;
  const size_t QKV_B  = (size_t)M1 * N1 * 2;
  const size_t XC_B   = (size_t)M1 * CH * 2;
  const size_t Y_B    = (size_t)M2 * K2 * 2;
  const size_t ARENA_OFF = QKV_B + 2*XC_B + Y_B;
  const size_t ARENA_B = 7543808L * 2;
  uint16_t* qkv = (uint16_t*)ws;
  float*    pre = (float*)ws;
  uint16_t* xcA = (uint16_t*)(ws + QKV_B);
  uint16_t* xcB = (uint16_t*)(ws + QKV_B + XC_B);
  uint16_t* y   = (uint16_t*)(ws + QKV_B + 2*XC_B);
  uint16_t* arena = (uint16_t*)(ws + ARENA_OFF);
  int*      flag  = (int*)(ws + ARENA_OFF + ARENA_B);

  const uint16_t* x_bf = arena;
  const uint16_t* wq[4] = {arena + 5640192, arena + 6033984, arena + 6427776, arena + 6821568};
  const uint16_t* aw[4] = {arena + 6033408, arena + 6427200, arena + 6820992, arena + 7214784};
  const uint16_t* gg[4] = {arena + 6033472, arena + 6427264, arena + 6821056, arena + 7214848};
  const uint16_t* bb[4] = {arena + 6033728, arena + 6427520, arena + 6821312, arena + 7215104};
  const uint16_t* pw = arena + 7215360;
  const uint16_t* pb = arena + 7543040;
  const uint16_t* gp = arena + 7543296;
  const uint16_t* bp = arena + 7543552;

  detect_kernel<<<1, 256, 0, stream>>>((const uint16_t*)d_in[0], flag);

  Ptrs ptrs;
  for (int i = 0; i < 21; i++) ptrs.p[i] = d_in[i];
  convert_kernel<<<3684, 256, 0, stream>>>(ptrs, flag, arena);

  prep_kernel<<<53696, 256, 0, stream>>>(x_bf, xcA, y);

  uint16_t* xcs[2] = {xcA, xcB};
  for (int L = 0; L < 4; ++L){
    gemm_bt<0><<<dim3(243, 12), 256, 0, stream>>>(xcs[L & 1], wq[L], qkv, M1, N1, K1);
    const int* ed = (L & 1) ? ecay : eskel;
    int E = (L & 1) ? 120 : 49;
    gat_kernel<<<F_FRAMES, 256, 0, stream>>>(qkv, xcs[L & 1], ed, aw[L], gg[L], bb[L],
                                             xcs[(L + 1) & 1], y, E, (L + 1) * 256);
  }
  gemm_bt<1><<<dim3(173, 2), 256, 0, stream>>>(y, pw, pre, M2, N2, K2);
  final_ln<<<5508, 256, 0, stream>>>(pre, pb, gp, bp, flag, d_out);
}